// Round 17
// baseline (506.357 us; speedup 1.0000x reference)
//
#include <hip/hip_runtime.h>
#include <cstdint>
#include <cstddef>

typedef unsigned short ushort_t;
typedef __attribute__((ext_vector_type(8))) short bf16x8;
typedef __attribute__((ext_vector_type(8))) unsigned short u16x8;
typedef __attribute__((ext_vector_type(4))) float f32x4;

#define T_TOKENS 8192
#define DIM      1024
#define NEXP     16

// ---------- helpers ----------
static __device__ __forceinline__ unsigned short f2bf(float f) {
  union { float f; unsigned u; } v; v.f = f;
  unsigned r = v.u + 0x7FFFu + ((v.u >> 16) & 1u);   // round-to-nearest-even
  return (unsigned short)(r >> 16);
}

static __device__ __forceinline__ void gload16(const void* g, void* l) {
  __builtin_amdgcn_global_load_lds(
      (const __attribute__((address_space(1))) unsigned int*)g,
      (__attribute__((address_space(3))) unsigned int*)l, 16, 0, 0);
}

// XCD-aware swizzle: each XCD (lin%8) owns a contiguous cb-range. Bijective
// (GX=64, gy in {8,16,32}).
static __device__ __forceinline__ void xcd_map(int bx, int by, int gy,
                                               int& rb, int& cb) {
  int lin = bx + (by << 6);        // GX = 64
  int xcd = lin & 7;
  int c = lin >> 3;
  int gyd = gy >> 3;               // gy/8
  cb = xcd * gyd + (c >> 6);
  rb = c & 63;
}

// ---------- fused: fp32->bf16 for all 7 tensors + gate scoring ----------
// blocks 0..31743: conversion segments; blocks 31744..33791: score (4 tok/blk)
__global__ __launch_bounds__(256) void k_cvt_score(
    const float* __restrict__ x,  const float* __restrict__ w1,
    const float* __restrict__ w2, const float* __restrict__ w3,
    const float* __restrict__ sw1, const float* __restrict__ sw2,
    const float* __restrict__ sw3, const float* __restrict__ gw,
    ushort_t* __restrict__ xb,  ushort_t* __restrict__ w1b,
    ushort_t* __restrict__ w2b, ushort_t* __restrict__ w3b,
    ushort_t* __restrict__ sw1b, ushort_t* __restrict__ sw2b,
    ushort_t* __restrict__ sw3b,
    int* __restrict__ sel0, int* __restrict__ sel1,
    float* __restrict__ w0o, float* __restrict__ w1o) {
  int b = blockIdx.x;
  if (b >= 31744) {
    // ---- score path: fp32 gate, top-2 per token ----
    int lane = threadIdx.x & 63;
    int wv = threadIdx.x >> 6;
    int t = (b - 31744) * 4 + wv;
    float xv[16];
    const float* xr = x + (size_t)t * DIM + lane * 16;
#pragma unroll
    for (int j = 0; j < 16; j += 4) {
      float4 v = *(const float4*)(xr + j);
      xv[j] = v.x; xv[j+1] = v.y; xv[j+2] = v.z; xv[j+3] = v.w;
    }
    float sc[NEXP];
#pragma unroll
    for (int e = 0; e < NEXP; e++) {
      const float* gr = gw + (size_t)e * DIM + lane * 16;
      float a = 0.f;
#pragma unroll
      for (int j = 0; j < 16; j += 4) {
        float4 g = *(const float4*)(gr + j);
        a += xv[j]*g.x + xv[j+1]*g.y + xv[j+2]*g.z + xv[j+3]*g.w;
      }
#pragma unroll
      for (int o = 32; o > 0; o >>= 1) a += __shfl_xor(a, o, 64);
      sc[e] = 1.f / (1.f + expf(-a));
    }
    if (lane == 0) {
      float best = -1e30f, sec = -1e30f;
      int bi = 0, si = 0;
#pragma unroll
      for (int e = 0; e < NEXP; e++) {
        float s = sc[e];
        if (s > best) { sec = best; si = bi; best = s; bi = e; }
        else if (s > sec) { sec = s; si = e; }
      }
      float inv = 1.f / (best + sec);
      sel0[t] = bi; sel1[t] = si;
      w0o[t] = best * inv; w1o[t] = sec * inv;
    }
    return;
  }
  // ---- conversion path ----
  const float* src; ushort_t* dst; int rel;
  if (b < 4096)       { src = x;   dst = xb;   rel = b; }
  else if (b < 12288) { src = w1;  dst = w1b;  rel = b - 4096; }
  else if (b < 20480) { src = w2;  dst = w2b;  rel = b - 12288; }
  else if (b < 28672) { src = w3;  dst = w3b;  rel = b - 20480; }
  else if (b < 29696) { src = sw1; dst = sw1b; rel = b - 28672; }
  else if (b < 30720) { src = sw2; dst = sw2b; rel = b - 29696; }
  else                { src = sw3; dst = sw3b; rel = b - 30720; }
  size_t i = ((size_t)rel * 256 + threadIdx.x) * 8;
  float4 a = *(const float4*)(src + i);
  float4 c = *(const float4*)(src + i + 4);
  u16x8 o;
  o[0]=f2bf(a.x); o[1]=f2bf(a.y); o[2]=f2bf(a.z); o[3]=f2bf(a.w);
  o[4]=f2bf(c.x); o[5]=f2bf(c.y); o[6]=f2bf(c.z); o[7]=f2bf(c.w);
  *(u16x8*)(dst + i) = o;
}

// ---------- compact: per-expert ordered token lists (deterministic) ----------
__global__ __launch_bounds__(256) void k_compact(const int* __restrict__ sel0,
                                                 const int* __restrict__ sel1,
                                                 const float* __restrict__ w0v,
                                                 const float* __restrict__ w1v,
                                                 int* __restrict__ toklist,
                                                 float* __restrict__ wlist,
                                                 int* __restrict__ cnt,
                                                 float* __restrict__ probs) {
  const int e = blockIdx.x;
  const int tid = threadIdx.x;
  const int lane = tid & 63, wv = tid >> 6;
  __shared__ int wbase[4];
  __shared__ int woff[4];
  __shared__ int base;
  __shared__ float pacc[4];
  if (tid == 0) base = 0;
  float myprob = 0.f;
  int* tl = toklist + e * T_TOKENS;
  float* wl = wlist + e * T_TOKENS;
  __syncthreads();
  for (int t0 = 0; t0 < T_TOKENS; t0 += 256) {
    int t = t0 + tid;
    bool m0 = (sel0[t] == e), m1 = (sel1[t] == e);
    bool m = m0 || m1;
    float wgt = m0 ? w0v[t] : (m1 ? w1v[t] : 0.f);
    unsigned long long bal = __ballot(m);
    int prefix = __popcll(bal & ((1ull << lane) - 1ull));
    if (lane == 0) wbase[wv] = __popcll(bal);
    __syncthreads();
    if (tid == 0) {
      int a = base;
#pragma unroll
      for (int i = 0; i < 4; i++) { woff[i] = a; a += wbase[i]; }
      base = a;
    }
    __syncthreads();
    if (m) {
      int pos = woff[wv] + prefix;
      tl[pos] = t;
      wl[pos] = wgt;
    }
    myprob += wgt;
  }
#pragma unroll
  for (int o = 32; o > 0; o >>= 1) myprob += __shfl_xor(myprob, o, 64);
  if (lane == 0) pacc[wv] = myprob;
  __syncthreads();
  if (tid == 0) {
    cnt[e] = base;
    probs[e] = pacc[0] + pacc[1] + pacc[2] + pacc[3];
  }
}

// ---------- prefix offsets + aux loss ----------
__global__ void k_offsets(const int* __restrict__ cnt, const float* __restrict__ probs,
                          int* __restrict__ seg, float* __restrict__ loss_out) {
  if (threadIdx.x == 0 && blockIdx.x == 0) {
    int acc = 0;
    float L = 0.f;
    for (int e = 0; e < NEXP; e++) {
      seg[e] = acc; acc += cnt[e];
      float f = 16.f * (float)cnt[e] / (2.f * 8192.f);
      L += f * (probs[e] / 8192.f);
    }
    seg[NEXP] = acc;
    *loss_out = L;
  }
}

// LDS tiles: [rows][64] bf16 (128B rows), XOR-swizzled over the 8 16B blocks
// per row by row&7 (r9/r12-verified: 0 bank conflicts). Written linearly by
// global_load_lds from a pre-swizzled SOURCE column; read with the same XOR.
// SINGLE buffer; classic 2-barrier loop — race-free family.

// ---------- GEMM1 (fused routed+shared): silu(X W1^T + b1)*(X W3^T + b3) ----
// r12 best config verbatim: 32KB LDS, 3 blocks/CU, 196us, MfmaUtil 31%.
__global__ __launch_bounds__(256, 3) void k_gemm1(
    const ushort_t* __restrict__ X,
    const ushort_t* __restrict__ w1b, const ushort_t* __restrict__ w3b,
    const ushort_t* __restrict__ sw1b, const ushort_t* __restrict__ sw3b,
    const float* __restrict__ sb1, const float* __restrict__ sb3,
    ushort_t* __restrict__ Pr, ushort_t* __restrict__ Ps,
    const int* __restrict__ toklist, const int* __restrict__ cnt,
    const int* __restrict__ seg, int zbase) {
  __shared__ __align__(16) ushort_t As[8192];    // 128 x 64
  __shared__ __align__(16) ushort_t B1s[4096];   // 64 x 64
  __shared__ __align__(16) ushort_t B3s[4096];

  const int tid = threadIdx.x;
  const int lane = tid & 63, wave = tid >> 6;
  const int wm = wave >> 1, wn = wave & 1;
  const int e = blockIdx.z + zbase;

  int rb, cb, Ne, pbase, ldP;
  const int* tl = nullptr;
  const ushort_t *W1, *W3;
  const float *b1 = nullptr, *b3 = nullptr;
  ushort_t* P;
  if (e < NEXP) {
    if (blockIdx.y >= 16) return;           // routed uses 16 cb-tiles
    xcd_map(blockIdx.x, blockIdx.y, 16, rb, cb);
    Ne = cnt[e];
    if (rb * 128 >= Ne) return;
    pbase = seg[e];
    tl = toklist + e * T_TOKENS;
    W1 = w1b + (size_t)e * 1024 * 1024;
    W3 = w3b + (size_t)e * 1024 * 1024;
    P = Pr; ldP = 1024;
  } else {
    xcd_map(blockIdx.x, blockIdx.y, 32, rb, cb);
    Ne = T_TOKENS; pbase = 0;
    W1 = sw1b; W3 = sw3b; b1 = sb1; b3 = sb3;
    P = Ps; ldP = 2048;
  }

  // staging: chunk = 8 rows x 64 cols (1KB). Source col pre-swizzled by row&7.
  const int lrow = lane >> 3;                 // 0..7
  const int scol = ((lane & 7) ^ lrow) * 8;   // inverse-swizzled source block

  // A: wave w -> chunks 4w..4w+3 (rows 32w..32w+31)
  const int ca = wave * 4;
  int ga0 = rb * 128 + (ca + 0) * 8 + lrow;
  int ga1 = rb * 128 + (ca + 1) * 8 + lrow;
  int ga2 = rb * 128 + (ca + 2) * 8 + lrow;
  int ga3 = rb * 128 + (ca + 3) * 8 + lrow;
  const int s0 = tl ? tl[min(ga0, Ne - 1)] : ga0;
  const int s1 = tl ? tl[min(ga1, Ne - 1)] : ga1;
  const int s2 = tl ? tl[min(ga2, Ne - 1)] : ga2;
  const int s3 = tl ? tl[min(ga3, Ne - 1)] : ga3;
  const ushort_t* apA0 = X + (size_t)s0 * DIM + scol;
  const ushort_t* apA1 = X + (size_t)s1 * DIM + scol;
  const ushort_t* apA2 = X + (size_t)s2 * DIM + scol;
  const ushort_t* apA3 = X + (size_t)s3 * DIM + scol;
  const int oa0 = (ca + 0) * 512, oa1 = (ca + 1) * 512;
  const int oa2 = (ca + 2) * 512, oa3 = (ca + 3) * 512;

  // B1/B3: wave w -> chunks 2w, 2w+1 (rows 16w..16w+15)
  const int brw0 = cb * 64 + wave * 16 + lrow;
  const int brw1 = brw0 + 8;
  const ushort_t* bp10 = W1 + (size_t)brw0 * DIM + scol;
  const ushort_t* bp11 = W1 + (size_t)brw1 * DIM + scol;
  const ushort_t* bp30 = W3 + (size_t)brw0 * DIM + scol;
  const ushort_t* bp31 = W3 + (size_t)brw1 * DIM + scol;
  const int ob0 = (wave * 2) * 512, ob1 = (wave * 2 + 1) * 512;

  // swizzled read offsets (per-lane constants), K-halves h=0,1
  const int ks0 = (((lane >> 4) + 0) ^ (lane & 7)) * 8;
  const int ks1 = (((lane >> 4) + 4) ^ (lane & 7)) * 8;

  f32x4 acc1[4][2], acc3[4][2];
#pragma unroll
  for (int m = 0; m < 4; m++)
#pragma unroll
    for (int n = 0; n < 2; n++) {
      acc1[m][n] = (f32x4){0.f, 0.f, 0.f, 0.f};
      acc3[m][n] = (f32x4){0.f, 0.f, 0.f, 0.f};
    }

#define HALF1(KS) { \
    bf16x8 af[4], b1f[2], b3f[2]; \
    _Pragma("unroll") \
    for (int m = 0; m < 4; m++) { \
      int row = wm * 64 + m * 16 + (lane & 15); \
      af[m] = *(const bf16x8*)(As + row * 64 + (KS)); } \
    _Pragma("unroll") \
    for (int n = 0; n < 2; n++) { \
      int rw = wn * 32 + n * 16 + (lane & 15); \
      b1f[n] = *(const bf16x8*)(B1s + rw * 64 + (KS)); \
      b3f[n] = *(const bf16x8*)(B3s + rw * 64 + (KS)); } \
    _Pragma("unroll") \
    for (int m = 0; m < 4; m++) \
      _Pragma("unroll") \
      for (int n = 0; n < 2; n++) { \
        acc1[m][n] = __builtin_amdgcn_mfma_f32_16x16x32_bf16(af[m], b1f[n], acc1[m][n], 0, 0, 0); \
        acc3[m][n] = __builtin_amdgcn_mfma_f32_16x16x32_bf16(af[m], b3f[n], acc3[m][n], 0, 0, 0); } }

  for (int t = 0; t < 16; ++t) {
    const int k0 = t * 64;
    gload16(apA0 + k0, As  + oa0);
    gload16(apA1 + k0, As  + oa1);
    gload16(apA2 + k0, As  + oa2);
    gload16(apA3 + k0, As  + oa3);
    gload16(bp10 + k0, B1s + ob0);
    gload16(bp11 + k0, B1s + ob1);
    gload16(bp30 + k0, B3s + ob0);
    gload16(bp31 + k0, B3s + ob1);
    __syncthreads();            // drain staging (vmcnt 0) + barrier
    HALF1(ks0);
    HALF1(ks1);
    __syncthreads();            // all reads done before next overwrite
  }
#undef HALF1

  // epilogue: silu(h1)*h3 -> bf16 P
#pragma unroll
  for (int n = 0; n < 2; n++) {
    int col = cb * 64 + wn * 32 + n * 16 + (lane & 15);
    float bb1 = b1 ? b1[col] : 0.f;
    float bb3 = b3 ? b3[col] : 0.f;
#pragma unroll
    for (int m = 0; m < 4; m++) {
#pragma unroll
      for (int r = 0; r < 4; r++) {
        int row = rb * 128 + wm * 64 + m * 16 + (lane >> 4) * 4 + r;
        if (row < Ne) {
          float h1 = acc1[m][n][r] + bb1;
          float h3 = acc3[m][n][r] + bb3;
          float pv = (h1 / (1.f + expf(-h1))) * h3;
          P[(size_t)(pbase + row) * ldP + col] = f2bf(pv);
        }
      }
    }
  }
}

// ---------- GEMM2 (fused 17z, 128x64 tiles, 5 blocks/CU): out += P W2^T ----
// All contributions via fp32 atomicAdd onto memset-zeroed out (shared adds
// b2). Small tile -> ~3000 valid blocks co-resident -> latency hidden by TLP.
__global__ __launch_bounds__(256, 5) void k_gemm2(
    const ushort_t* __restrict__ Pr, const ushort_t* __restrict__ Ps,
    const ushort_t* __restrict__ w2b, const ushort_t* __restrict__ sw2b,
    const float* __restrict__ sb2,
    float* __restrict__ outp,
    const int* __restrict__ toklist, const float* __restrict__ wlist,
    const int* __restrict__ cnt, const int* __restrict__ seg, int zbase) {
  __shared__ __align__(16) ushort_t As[8192];   // 128 x 64 (P rows)
  __shared__ __align__(16) ushort_t Bs[4096];   //  64 x 64 (W2 rows)

  const int tid = threadIdx.x;
  const int lane = tid & 63, wave = tid >> 6;
  const int wm = wave >> 1, wn = wave & 1;
  const int e = blockIdx.z + zbase;
  int rb, cb;
  xcd_map(blockIdx.x, blockIdx.y, 16, rb, cb);   // gy = 16 col-tiles of 64

  int Ne, Kd;
  const ushort_t *A, *W2;
  const int* tl = nullptr; const float* wl = nullptr;
  const float* b2 = nullptr;
  if (e < NEXP) {
    Ne = cnt[e];
    if (rb * 128 >= Ne) return;
    A = Pr + (size_t)seg[e] * 1024;
    W2 = w2b + (size_t)e * 1024 * 1024;
    tl = toklist + e * T_TOKENS;
    wl = wlist + e * T_TOKENS;
    Kd = 1024;
  } else {
    Ne = T_TOKENS;
    A = Ps; W2 = sw2b; b2 = sb2; Kd = 2048;
  }

  const int lrow = lane >> 3;
  const int scol = ((lane & 7) ^ lrow) * 8;

  // A: wave w -> chunks 4w..4w+3 (rows 32w..32w+31 of 128)
  const int ca = wave * 4;
  const int a0 = min(rb * 128 + (ca + 0) * 8 + lrow, Ne - 1);
  const int a1 = min(rb * 128 + (ca + 1) * 8 + lrow, Ne - 1);
  const int a2 = min(rb * 128 + (ca + 2) * 8 + lrow, Ne - 1);
  const int a3 = min(rb * 128 + (ca + 3) * 8 + lrow, Ne - 1);
  const ushort_t* apA0 = A + (size_t)a0 * Kd + scol;
  const ushort_t* apA1 = A + (size_t)a1 * Kd + scol;
  const ushort_t* apA2 = A + (size_t)a2 * Kd + scol;
  const ushort_t* apA3 = A + (size_t)a3 * Kd + scol;
  const int oa0 = (ca + 0) * 512, oa1 = (ca + 1) * 512;
  const int oa2 = (ca + 2) * 512, oa3 = (ca + 3) * 512;

  // B: 64 rows -> wave w stages chunks 2w, 2w+1 (rows 16w..16w+15)
  const int brw0 = cb * 64 + wave * 16 + lrow;
  const int brw1 = brw0 + 8;
  const ushort_t* bp0 = W2 + (size_t)brw0 * Kd + scol;
  const ushort_t* bp1 = W2 + (size_t)brw1 * Kd + scol;
  const int ob0 = (wave * 2) * 512, ob1 = (wave * 2 + 1) * 512;

  const int ks0 = (((lane >> 4) + 0) ^ (lane & 7)) * 8;
  const int ks1 = (((lane >> 4) + 4) ^ (lane & 7)) * 8;

  f32x4 acc[4][2];
#pragma unroll
  for (int m = 0; m < 4; m++)
#pragma unroll
    for (int n = 0; n < 2; n++) acc[m][n] = (f32x4){0.f, 0.f, 0.f, 0.f};

  const int ksteps = Kd >> 6;

#define HALF2(KS) { \
    bf16x8 af[4], bf[2]; \
    _Pragma("unroll") \
    for (int m = 0; m < 4; m++) { \
      int row = wm * 64 + m * 16 + (lane & 15); \
      af[m] = *(const bf16x8*)(As + row * 64 + (KS)); } \
    _Pragma("unroll") \
    for (int n = 0; n < 2; n++) { \
      int rw = wn * 32 + n * 16 + (lane & 15); \
      bf[n] = *(const bf16x8*)(Bs + rw * 64 + (KS)); } \
    _Pragma("unroll") \
    for (int m = 0; m < 4; m++) \
      _Pragma("unroll") \
      for (int n = 0; n < 2; n++) \
        acc[m][n] = __builtin_amdgcn_mfma_f32_16x16x32_bf16(af[m], bf[n], acc[m][n], 0, 0, 0); }

  for (int t = 0; t < ksteps; ++t) {
    const int k0 = t * 64;
    gload16(apA0 + k0, As + oa0);
    gload16(apA1 + k0, As + oa1);
    gload16(apA2 + k0, As + oa2);
    gload16(apA3 + k0, As + oa3);
    gload16(bp0  + k0, Bs + ob0);
    gload16(bp1  + k0, Bs + ob1);
    __syncthreads();
    HALF2(ks0);
    HALF2(ks1);
    __syncthreads();
  }
#undef HALF2

#pragma unroll
  for (int n = 0; n < 2; n++) {
    int col = cb * 64 + wn * 32 + n * 16 + (lane & 15);
    float bias = b2 ? b2[col] : 0.f;
#pragma unroll
    for (int m = 0; m < 4; m++) {
#pragma unroll
      for (int r = 0; r < 4; r++) {
        int rl = rb * 128 + wm * 64 + m * 16 + (lane >> 4) * 4 + r;
        if (e < NEXP) {
          if (rl < Ne) {
            int tok = tl[rl];
            float wgt = wl[rl];
            atomicAdd(outp + (size_t)tok * DIM + col, acc[m][n][r] * wgt);
          }
        } else {
          atomicAdd(outp + (size_t)rl * DIM + col, acc[m][n][r] + bias);
        }
      }
    }
  }
}

// ---------- launch ----------
extern "C" void kernel_launch(void* const* d_in, const int* in_sizes, int n_in,
                              void* d_out, int out_size, void* d_ws, size_t ws_size,
                              hipStream_t stream) {
  const float* x   = (const float*)d_in[0];
  const float* gw  = (const float*)d_in[1];
  const float* w1  = (const float*)d_in[2];
  const float* w2  = (const float*)d_in[3];
  const float* w3  = (const float*)d_in[4];
  const float* sw1 = (const float*)d_in[5];
  const float* sb1 = (const float*)d_in[6];
  const float* sw2 = (const float*)d_in[7];
  const float* sb2 = (const float*)d_in[8];
  const float* sw3 = (const float*)d_in[9];
  const float* sb3 = (const float*)d_in[10];
  float* out  = (float*)d_out;
  float* loss = out + (size_t)T_TOKENS * DIM;

  const size_t NW = (size_t)NEXP * 1024 * 1024;   // elems per routed weight tensor
  const size_t NS = (size_t)2048 * 1024;          // elems per shared weight tensor
  const size_t PSZ = (size_t)16384 * 1024 * 2;    // 33.55 MB (one P region)

  char* w = (char*)d_ws;
  ushort_t* w1b  = (ushort_t*)w; w += NW * 2;
  ushort_t* w2b  = (ushort_t*)w; w += NW * 2;
  ushort_t* w3b  = (ushort_t*)w; w += NW * 2;
  ushort_t* sw1b = (ushort_t*)w; w += NS * 2;
  ushort_t* sw2b = (ushort_t*)w; w += NS * 2;
  ushort_t* sw3b = (ushort_t*)w; w += NS * 2;
  ushort_t* Pr   = (ushort_t*)w; w += PSZ;
  ushort_t* x_bf = (ushort_t*)w; w += (size_t)T_TOKENS * DIM * 2;
  int*   toklist = (int*)w;      w += (size_t)NEXP * T_TOKENS * 4;
  float* wlist   = (float*)w;    w += (size_t)NEXP * T_TOKENS * 4;
  int*   sel0    = (int*)w;      w += (size_t)T_TOKENS * 4;
  int*   sel1    = (int*)w;      w += (size_t)T_TOKENS * 4;
  float* w0v     = (float*)w;    w += (size_t)T_TOKENS * 4;
  float* w1v     = (float*)w;    w += (size_t)T_TOKENS * 4;
  int*   cnt     = (int*)w;      w += 64;
  float* probs   = (float*)w;    w += 64;
  int*   seg     = (int*)w;      w += 128;

  // fused gemm1 needs a second P region; fall back to sequential if tight
  size_t used = (size_t)(w - (char*)d_ws);
  bool fused = (used + PSZ + 1024) <= ws_size;
  ushort_t* Ps = fused ? (ushort_t*)w : Pr;

  // zero output (gemm2 accumulates via atomicAdd; loss written by k_offsets)
  hipMemsetAsync(d_out, 0, (size_t)out_size * 4, stream);

  // fp32 -> bf16 (7 tensors) + gate scoring, one dispatch
  k_cvt_score<<<33792, 256, 0, stream>>>(x, w1, w2, w3, sw1, sw2, sw3, gw,
                                         x_bf, w1b, w2b, w3b, sw1b, sw2b, sw3b,
                                         sel0, sel1, w0v, w1v);

  k_compact<<<NEXP, 256, 0, stream>>>(sel0, sel1, w0v, w1v,
                                      toklist, wlist, cnt, probs);
  k_offsets<<<1, 64, 0, stream>>>(cnt, probs, seg, loss);

  if (fused) {
    k_gemm1<<<dim3(64, 32, 17), 256, 0, stream>>>(
        x_bf, w1b, w3b, sw1b, sw3b, sb1, sb3, Pr, Ps,
        toklist, cnt, seg, 0);
    // one gemm2 dispatch: z 0..15 routed + z 16 shared, 128x64 tiles
    k_gemm2<<<dim3(64, 16, 17), 256, 0, stream>>>(
        Pr, Ps, w2b, sw2b, sb2, out, toklist, wlist, cnt, seg, 0);
  } else {
    // sequential fallback (Ps aliases Pr): shared chain then routed chain
    k_gemm1<<<dim3(64, 32, 1), 256, 0, stream>>>(
        x_bf, w1b, w3b, sw1b, sw3b, sb1, sb3, Pr, Ps,
        toklist, cnt, seg, 16);
    k_gemm2<<<dim3(64, 16, 1), 256, 0, stream>>>(
        Pr, Ps, w2b, sw2b, sb2, out, toklist, wlist, cnt, seg, 16);
    k_gemm1<<<dim3(64, 16, 16), 256, 0, stream>>>(
        x_bf, w1b, w3b, sw1b, sw3b, sb1, sb3, Pr, Ps,
        toklist, cnt, seg, 0);
    k_gemm2<<<dim3(64, 16, 16), 256, 0, stream>>>(
        Pr, Ps, w2b, sw2b, sb2, out, toklist, wlist, cnt, seg, 0);
  }
}

// Round 18
// 481.009 us; speedup vs baseline: 1.0527x; 1.0527x over previous
//
#include <hip/hip_runtime.h>
#include <cstdint>
#include <cstddef>

typedef unsigned short ushort_t;
typedef __attribute__((ext_vector_type(8))) short bf16x8;
typedef __attribute__((ext_vector_type(8))) unsigned short u16x8;
typedef __attribute__((ext_vector_type(4))) float f32x4;

#define T_TOKENS 8192
#define DIM      1024
#define NEXP     16

// ---------- helpers ----------
static __device__ __forceinline__ unsigned short f2bf(float f) {
  union { float f; unsigned u; } v; v.f = f;
  unsigned r = v.u + 0x7FFFu + ((v.u >> 16) & 1u);   // round-to-nearest-even
  return (unsigned short)(r >> 16);
}

static __device__ __forceinline__ void gload16(const void* g, void* l) {
  __builtin_amdgcn_global_load_lds(
      (const __attribute__((address_space(1))) unsigned int*)g,
      (__attribute__((address_space(3))) unsigned int*)l, 16, 0, 0);
}

// XCD-aware swizzle: each XCD (lin%8) owns a contiguous cb-range. Bijective
// (GX=64, gy in {8,16,32}).
static __device__ __forceinline__ void xcd_map(int bx, int by, int gy,
                                               int& rb, int& cb) {
  int lin = bx + (by << 6);        // GX = 64
  int xcd = lin & 7;
  int c = lin >> 3;
  int gyd = gy >> 3;               // gy/8
  cb = xcd * gyd + (c >> 6);
  rb = c & 63;
}

// ---------- fused: fp32->bf16 for all 7 tensors + gate scoring ----------
// blocks 0..31743: conversion segments; blocks 31744..33791: score (4 tok/blk)
__global__ __launch_bounds__(256) void k_cvt_score(
    const float* __restrict__ x,  const float* __restrict__ w1,
    const float* __restrict__ w2, const float* __restrict__ w3,
    const float* __restrict__ sw1, const float* __restrict__ sw2,
    const float* __restrict__ sw3, const float* __restrict__ gw,
    ushort_t* __restrict__ xb,  ushort_t* __restrict__ w1b,
    ushort_t* __restrict__ w2b, ushort_t* __restrict__ w3b,
    ushort_t* __restrict__ sw1b, ushort_t* __restrict__ sw2b,
    ushort_t* __restrict__ sw3b,
    int* __restrict__ sel0, int* __restrict__ sel1,
    float* __restrict__ w0o, float* __restrict__ w1o) {
  int b = blockIdx.x;
  if (b >= 31744) {
    // ---- score path: fp32 gate, top-2 per token ----
    int lane = threadIdx.x & 63;
    int wv = threadIdx.x >> 6;
    int t = (b - 31744) * 4 + wv;
    float xv[16];
    const float* xr = x + (size_t)t * DIM + lane * 16;
#pragma unroll
    for (int j = 0; j < 16; j += 4) {
      float4 v = *(const float4*)(xr + j);
      xv[j] = v.x; xv[j+1] = v.y; xv[j+2] = v.z; xv[j+3] = v.w;
    }
    float sc[NEXP];
#pragma unroll
    for (int e = 0; e < NEXP; e++) {
      const float* gr = gw + (size_t)e * DIM + lane * 16;
      float a = 0.f;
#pragma unroll
      for (int j = 0; j < 16; j += 4) {
        float4 g = *(const float4*)(gr + j);
        a += xv[j]*g.x + xv[j+1]*g.y + xv[j+2]*g.z + xv[j+3]*g.w;
      }
#pragma unroll
      for (int o = 32; o > 0; o >>= 1) a += __shfl_xor(a, o, 64);
      sc[e] = 1.f / (1.f + expf(-a));
    }
    if (lane == 0) {
      float best = -1e30f, sec = -1e30f;
      int bi = 0, si = 0;
#pragma unroll
      for (int e = 0; e < NEXP; e++) {
        float s = sc[e];
        if (s > best) { sec = best; si = bi; best = s; bi = e; }
        else if (s > sec) { sec = s; si = e; }
      }
      float inv = 1.f / (best + sec);
      sel0[t] = bi; sel1[t] = si;
      w0o[t] = best * inv; w1o[t] = sec * inv;
    }
    return;
  }
  // ---- conversion path ----
  const float* src; ushort_t* dst; int rel;
  if (b < 4096)       { src = x;   dst = xb;   rel = b; }
  else if (b < 12288) { src = w1;  dst = w1b;  rel = b - 4096; }
  else if (b < 20480) { src = w2;  dst = w2b;  rel = b - 12288; }
  else if (b < 28672) { src = w3;  dst = w3b;  rel = b - 20480; }
  else if (b < 29696) { src = sw1; dst = sw1b; rel = b - 28672; }
  else if (b < 30720) { src = sw2; dst = sw2b; rel = b - 29696; }
  else                { src = sw3; dst = sw3b; rel = b - 30720; }
  size_t i = ((size_t)rel * 256 + threadIdx.x) * 8;
  float4 a = *(const float4*)(src + i);
  float4 c = *(const float4*)(src + i + 4);
  u16x8 o;
  o[0]=f2bf(a.x); o[1]=f2bf(a.y); o[2]=f2bf(a.z); o[3]=f2bf(a.w);
  o[4]=f2bf(c.x); o[5]=f2bf(c.y); o[6]=f2bf(c.z); o[7]=f2bf(c.w);
  *(u16x8*)(dst + i) = o;
}

// ---------- compact: per-expert ordered token lists (deterministic) ----------
__global__ __launch_bounds__(256) void k_compact(const int* __restrict__ sel0,
                                                 const int* __restrict__ sel1,
                                                 const float* __restrict__ w0v,
                                                 const float* __restrict__ w1v,
                                                 int* __restrict__ toklist,
                                                 float* __restrict__ wlist,
                                                 int* __restrict__ cnt,
                                                 float* __restrict__ probs) {
  const int e = blockIdx.x;
  const int tid = threadIdx.x;
  const int lane = tid & 63, wv = tid >> 6;
  __shared__ int wbase[4];
  __shared__ int woff[4];
  __shared__ int base;
  __shared__ float pacc[4];
  if (tid == 0) base = 0;
  float myprob = 0.f;
  int* tl = toklist + e * T_TOKENS;
  float* wl = wlist + e * T_TOKENS;
  __syncthreads();
  for (int t0 = 0; t0 < T_TOKENS; t0 += 256) {
    int t = t0 + tid;
    bool m0 = (sel0[t] == e), m1 = (sel1[t] == e);
    bool m = m0 || m1;
    float wgt = m0 ? w0v[t] : (m1 ? w1v[t] : 0.f);
    unsigned long long bal = __ballot(m);
    int prefix = __popcll(bal & ((1ull << lane) - 1ull));
    if (lane == 0) wbase[wv] = __popcll(bal);
    __syncthreads();
    if (tid == 0) {
      int a = base;
#pragma unroll
      for (int i = 0; i < 4; i++) { woff[i] = a; a += wbase[i]; }
      base = a;
    }
    __syncthreads();
    if (m) {
      int pos = woff[wv] + prefix;
      tl[pos] = t;
      wl[pos] = wgt;
    }
    myprob += wgt;
  }
#pragma unroll
  for (int o = 32; o > 0; o >>= 1) myprob += __shfl_xor(myprob, o, 64);
  if (lane == 0) pacc[wv] = myprob;
  __syncthreads();
  if (tid == 0) {
    cnt[e] = base;
    probs[e] = pacc[0] + pacc[1] + pacc[2] + pacc[3];
  }
}

// ---------- prefix offsets + aux loss ----------
__global__ void k_offsets(const int* __restrict__ cnt, const float* __restrict__ probs,
                          int* __restrict__ seg, float* __restrict__ loss_out) {
  if (threadIdx.x == 0 && blockIdx.x == 0) {
    int acc = 0;
    float L = 0.f;
    for (int e = 0; e < NEXP; e++) {
      seg[e] = acc; acc += cnt[e];
      float f = 16.f * (float)cnt[e] / (2.f * 8192.f);
      L += f * (probs[e] / 8192.f);
    }
    seg[NEXP] = acc;
    *loss_out = L;
  }
}

// LDS tiles: [rows][64] bf16 (128B rows), XOR-swizzled over the 8 16B blocks
// per row by row&7 (r9/r12-verified: 0 bank conflicts). Written linearly by
// global_load_lds from a pre-swizzled SOURCE column; read with the same XOR.
// SINGLE buffer (32KB total) -> 3 blocks/CU; classic 2-barrier loop
// [stage; sync; compute 2 K-halves (32 MFMA/wave); sync] — race-free family.
// (r12/r16 best config: 196us fused gemm1, MfmaUtil 31%, conflicts 0.)

// ---------- GEMM1 (fused routed+shared): silu(X W1^T + b1)*(X W3^T + b3) ----
__global__ __launch_bounds__(256, 3) void k_gemm1(
    const ushort_t* __restrict__ X,
    const ushort_t* __restrict__ w1b, const ushort_t* __restrict__ w3b,
    const ushort_t* __restrict__ sw1b, const ushort_t* __restrict__ sw3b,
    const float* __restrict__ sb1, const float* __restrict__ sb3,
    ushort_t* __restrict__ Pr, ushort_t* __restrict__ Ps,
    const int* __restrict__ toklist, const int* __restrict__ cnt,
    const int* __restrict__ seg, int zbase) {
  __shared__ __align__(16) ushort_t As[8192];    // 128 x 64
  __shared__ __align__(16) ushort_t B1s[4096];   // 64 x 64
  __shared__ __align__(16) ushort_t B3s[4096];

  const int tid = threadIdx.x;
  const int lane = tid & 63, wave = tid >> 6;
  const int wm = wave >> 1, wn = wave & 1;
  const int e = blockIdx.z + zbase;

  int rb, cb, Ne, pbase, ldP;
  const int* tl = nullptr;
  const ushort_t *W1, *W3;
  const float *b1 = nullptr, *b3 = nullptr;
  ushort_t* P;
  if (e < NEXP) {
    if (blockIdx.y >= 16) return;           // routed uses 16 cb-tiles
    xcd_map(blockIdx.x, blockIdx.y, 16, rb, cb);
    Ne = cnt[e];
    if (rb * 128 >= Ne) return;
    pbase = seg[e];
    tl = toklist + e * T_TOKENS;
    W1 = w1b + (size_t)e * 1024 * 1024;
    W3 = w3b + (size_t)e * 1024 * 1024;
    P = Pr; ldP = 1024;
  } else {
    xcd_map(blockIdx.x, blockIdx.y, 32, rb, cb);
    Ne = T_TOKENS; pbase = 0;
    W1 = sw1b; W3 = sw3b; b1 = sb1; b3 = sb3;
    P = Ps; ldP = 2048;
  }

  // staging: chunk = 8 rows x 64 cols (1KB). Source col pre-swizzled by row&7.
  const int lrow = lane >> 3;                 // 0..7
  const int scol = ((lane & 7) ^ lrow) * 8;   // inverse-swizzled source block

  // A: wave w -> chunks 4w..4w+3 (rows 32w..32w+31)
  const int ca = wave * 4;
  int ga0 = rb * 128 + (ca + 0) * 8 + lrow;
  int ga1 = rb * 128 + (ca + 1) * 8 + lrow;
  int ga2 = rb * 128 + (ca + 2) * 8 + lrow;
  int ga3 = rb * 128 + (ca + 3) * 8 + lrow;
  const int s0 = tl ? tl[min(ga0, Ne - 1)] : ga0;
  const int s1 = tl ? tl[min(ga1, Ne - 1)] : ga1;
  const int s2 = tl ? tl[min(ga2, Ne - 1)] : ga2;
  const int s3 = tl ? tl[min(ga3, Ne - 1)] : ga3;
  const ushort_t* apA0 = X + (size_t)s0 * DIM + scol;
  const ushort_t* apA1 = X + (size_t)s1 * DIM + scol;
  const ushort_t* apA2 = X + (size_t)s2 * DIM + scol;
  const ushort_t* apA3 = X + (size_t)s3 * DIM + scol;
  const int oa0 = (ca + 0) * 512, oa1 = (ca + 1) * 512;
  const int oa2 = (ca + 2) * 512, oa3 = (ca + 3) * 512;

  // B1/B3: wave w -> chunks 2w, 2w+1 (rows 16w..16w+15)
  const int brw0 = cb * 64 + wave * 16 + lrow;
  const int brw1 = brw0 + 8;
  const ushort_t* bp10 = W1 + (size_t)brw0 * DIM + scol;
  const ushort_t* bp11 = W1 + (size_t)brw1 * DIM + scol;
  const ushort_t* bp30 = W3 + (size_t)brw0 * DIM + scol;
  const ushort_t* bp31 = W3 + (size_t)brw1 * DIM + scol;
  const int ob0 = (wave * 2) * 512, ob1 = (wave * 2 + 1) * 512;

  // swizzled read offsets (per-lane constants), K-halves h=0,1
  const int ks0 = (((lane >> 4) + 0) ^ (lane & 7)) * 8;
  const int ks1 = (((lane >> 4) + 4) ^ (lane & 7)) * 8;

  f32x4 acc1[4][2], acc3[4][2];
#pragma unroll
  for (int m = 0; m < 4; m++)
#pragma unroll
    for (int n = 0; n < 2; n++) {
      acc1[m][n] = (f32x4){0.f, 0.f, 0.f, 0.f};
      acc3[m][n] = (f32x4){0.f, 0.f, 0.f, 0.f};
    }

#define HALF1(KS) { \
    bf16x8 af[4], b1f[2], b3f[2]; \
    _Pragma("unroll") \
    for (int m = 0; m < 4; m++) { \
      int row = wm * 64 + m * 16 + (lane & 15); \
      af[m] = *(const bf16x8*)(As + row * 64 + (KS)); } \
    _Pragma("unroll") \
    for (int n = 0; n < 2; n++) { \
      int rw = wn * 32 + n * 16 + (lane & 15); \
      b1f[n] = *(const bf16x8*)(B1s + rw * 64 + (KS)); \
      b3f[n] = *(const bf16x8*)(B3s + rw * 64 + (KS)); } \
    _Pragma("unroll") \
    for (int m = 0; m < 4; m++) \
      _Pragma("unroll") \
      for (int n = 0; n < 2; n++) { \
        acc1[m][n] = __builtin_amdgcn_mfma_f32_16x16x32_bf16(af[m], b1f[n], acc1[m][n], 0, 0, 0); \
        acc3[m][n] = __builtin_amdgcn_mfma_f32_16x16x32_bf16(af[m], b3f[n], acc3[m][n], 0, 0, 0); } }

  for (int t = 0; t < 16; ++t) {
    const int k0 = t * 64;
    gload16(apA0 + k0, As  + oa0);
    gload16(apA1 + k0, As  + oa1);
    gload16(apA2 + k0, As  + oa2);
    gload16(apA3 + k0, As  + oa3);
    gload16(bp10 + k0, B1s + ob0);
    gload16(bp11 + k0, B1s + ob1);
    gload16(bp30 + k0, B3s + ob0);
    gload16(bp31 + k0, B3s + ob1);
    __syncthreads();            // drain staging (vmcnt 0) + barrier
    HALF1(ks0);
    HALF1(ks1);
    __syncthreads();            // all reads done before next overwrite
  }
#undef HALF1

  // epilogue: silu(h1)*h3 -> bf16 P
#pragma unroll
  for (int n = 0; n < 2; n++) {
    int col = cb * 64 + wn * 32 + n * 16 + (lane & 15);
    float bb1 = b1 ? b1[col] : 0.f;
    float bb3 = b3 ? b3[col] : 0.f;
#pragma unroll
    for (int m = 0; m < 4; m++) {
#pragma unroll
      for (int r = 0; r < 4; r++) {
        int row = rb * 128 + wm * 64 + m * 16 + (lane >> 4) * 4 + r;
        if (row < Ne) {
          float h1 = acc1[m][n][r] + bb1;
          float h3 = acc3[m][n][r] + bb3;
          float pv = (h1 / (1.f + expf(-h1))) * h3;
          P[(size_t)(pbase + row) * ldP + col] = f2bf(pv);
        }
      }
    }
  }
}

// ---------- GEMM2: out = P W2^T (routed: *wgt atomic; shared: store + b2) ----
__global__ __launch_bounds__(256, 3) void k_gemm2(
    const ushort_t* __restrict__ Pr, const ushort_t* __restrict__ Ps,
    const ushort_t* __restrict__ w2b, const ushort_t* __restrict__ sw2b,
    const float* __restrict__ sb2,
    float* __restrict__ outp,
    const int* __restrict__ toklist, const float* __restrict__ wlist,
    const int* __restrict__ cnt, const int* __restrict__ seg, int zbase) {
  __shared__ __align__(16) ushort_t As[8192];   // 128 x 64
  __shared__ __align__(16) ushort_t Bs[8192];   // 128 x 64

  const int tid = threadIdx.x;
  const int lane = tid & 63, wave = tid >> 6;
  const int wm = wave >> 1, wn = wave & 1;
  const int e = blockIdx.z + zbase;
  int rb, cb;
  xcd_map(blockIdx.x, blockIdx.y, 8, rb, cb);

  int Ne, Kd;
  const ushort_t *A, *W2;
  const int* tl = nullptr; const float* wl = nullptr;
  const float* b2 = nullptr;
  if (e < NEXP) {
    Ne = cnt[e];
    if (rb * 128 >= Ne) return;
    A = Pr + (size_t)seg[e] * 1024;
    W2 = w2b + (size_t)e * 1024 * 1024;
    tl = toklist + e * T_TOKENS;
    wl = wlist + e * T_TOKENS;
    Kd = 1024;
  } else {
    Ne = T_TOKENS;
    A = Ps; W2 = sw2b; b2 = sb2; Kd = 2048;
  }

  const int lrow = lane >> 3;
  const int scol = ((lane & 7) ^ lrow) * 8;

  const int ca = wave * 4;
  const int a0 = min(rb * 128 + (ca + 0) * 8 + lrow, Ne - 1);
  const int a1 = min(rb * 128 + (ca + 1) * 8 + lrow, Ne - 1);
  const int a2 = min(rb * 128 + (ca + 2) * 8 + lrow, Ne - 1);
  const int a3 = min(rb * 128 + (ca + 3) * 8 + lrow, Ne - 1);
  const ushort_t* apA0 = A + (size_t)a0 * Kd + scol;
  const ushort_t* apA1 = A + (size_t)a1 * Kd + scol;
  const ushort_t* apA2 = A + (size_t)a2 * Kd + scol;
  const ushort_t* apA3 = A + (size_t)a3 * Kd + scol;
  const int oa0 = (ca + 0) * 512, oa1 = (ca + 1) * 512;
  const int oa2 = (ca + 2) * 512, oa3 = (ca + 3) * 512;

  const int br0 = cb * 128 + (ca + 0) * 8 + lrow;
  const int br1 = cb * 128 + (ca + 1) * 8 + lrow;
  const int br2 = cb * 128 + (ca + 2) * 8 + lrow;
  const int br3 = cb * 128 + (ca + 3) * 8 + lrow;
  const ushort_t* bp0 = W2 + (size_t)br0 * Kd + scol;
  const ushort_t* bp1 = W2 + (size_t)br1 * Kd + scol;
  const ushort_t* bp2 = W2 + (size_t)br2 * Kd + scol;
  const ushort_t* bp3 = W2 + (size_t)br3 * Kd + scol;

  const int ks0 = (((lane >> 4) + 0) ^ (lane & 7)) * 8;
  const int ks1 = (((lane >> 4) + 4) ^ (lane & 7)) * 8;

  f32x4 acc[4][4];
#pragma unroll
  for (int m = 0; m < 4; m++)
#pragma unroll
    for (int n = 0; n < 4; n++) acc[m][n] = (f32x4){0.f, 0.f, 0.f, 0.f};

  const int ksteps = Kd >> 6;

#define HALF2(KS) { \
    bf16x8 af[4], bf[4]; \
    _Pragma("unroll") \
    for (int m = 0; m < 4; m++) { \
      int row = wm * 64 + m * 16 + (lane & 15); \
      af[m] = *(const bf16x8*)(As + row * 64 + (KS)); } \
    _Pragma("unroll") \
    for (int n = 0; n < 4; n++) { \
      int rw = wn * 64 + n * 16 + (lane & 15); \
      bf[n] = *(const bf16x8*)(Bs + rw * 64 + (KS)); } \
    _Pragma("unroll") \
    for (int m = 0; m < 4; m++) \
      _Pragma("unroll") \
      for (int n = 0; n < 4; n++) \
        acc[m][n] = __builtin_amdgcn_mfma_f32_16x16x32_bf16(af[m], bf[n], acc[m][n], 0, 0, 0); }

  for (int t = 0; t < ksteps; ++t) {
    const int k0 = t * 64;
    gload16(apA0 + k0, As + oa0);
    gload16(apA1 + k0, As + oa1);
    gload16(apA2 + k0, As + oa2);
    gload16(apA3 + k0, As + oa3);
    gload16(bp0  + k0, Bs + oa0);
    gload16(bp1  + k0, Bs + oa1);
    gload16(bp2  + k0, Bs + oa2);
    gload16(bp3  + k0, Bs + oa3);
    __syncthreads();
    HALF2(ks0);
    HALF2(ks1);
    __syncthreads();
  }
#undef HALF2

#pragma unroll
  for (int n = 0; n < 4; n++) {
    int col = cb * 128 + wn * 64 + n * 16 + (lane & 15);
    float bias = b2 ? b2[col] : 0.f;
#pragma unroll
    for (int m = 0; m < 4; m++) {
#pragma unroll
      for (int r = 0; r < 4; r++) {
        int rl = rb * 128 + wm * 64 + m * 16 + (lane >> 4) * 4 + r;
        if (e < NEXP) {
          if (rl < Ne) {
            int tok = tl[rl];
            float wgt = wl[rl];
            atomicAdd(outp + (size_t)tok * DIM + col, acc[m][n][r] * wgt);
          }
        } else {
          outp[(size_t)rl * DIM + col] = acc[m][n][r] + bias;  // plain store
        }
      }
    }
  }
}

// ---------- launch ----------
extern "C" void kernel_launch(void* const* d_in, const int* in_sizes, int n_in,
                              void* d_out, int out_size, void* d_ws, size_t ws_size,
                              hipStream_t stream) {
  const float* x   = (const float*)d_in[0];
  const float* gw  = (const float*)d_in[1];
  const float* w1  = (const float*)d_in[2];
  const float* w2  = (const float*)d_in[3];
  const float* w3  = (const float*)d_in[4];
  const float* sw1 = (const float*)d_in[5];
  const float* sb1 = (const float*)d_in[6];
  const float* sw2 = (const float*)d_in[7];
  const float* sb2 = (const float*)d_in[8];
  const float* sw3 = (const float*)d_in[9];
  const float* sb3 = (const float*)d_in[10];
  float* out  = (float*)d_out;
  float* loss = out + (size_t)T_TOKENS * DIM;

  const size_t NW = (size_t)NEXP * 1024 * 1024;   // elems per routed weight tensor
  const size_t NS = (size_t)2048 * 1024;          // elems per shared weight tensor
  const size_t PSZ = (size_t)16384 * 1024 * 2;    // 33.55 MB (one P region)

  char* w = (char*)d_ws;
  ushort_t* w1b  = (ushort_t*)w; w += NW * 2;
  ushort_t* w2b  = (ushort_t*)w; w += NW * 2;
  ushort_t* w3b  = (ushort_t*)w; w += NW * 2;
  ushort_t* sw1b = (ushort_t*)w; w += NS * 2;
  ushort_t* sw2b = (ushort_t*)w; w += NS * 2;
  ushort_t* sw3b = (ushort_t*)w; w += NS * 2;
  ushort_t* Pr   = (ushort_t*)w; w += PSZ;
  ushort_t* x_bf = (ushort_t*)w; w += (size_t)T_TOKENS * DIM * 2;
  int*   toklist = (int*)w;      w += (size_t)NEXP * T_TOKENS * 4;
  float* wlist   = (float*)w;    w += (size_t)NEXP * T_TOKENS * 4;
  int*   sel0    = (int*)w;      w += (size_t)T_TOKENS * 4;
  int*   sel1    = (int*)w;      w += (size_t)T_TOKENS * 4;
  float* w0v     = (float*)w;    w += (size_t)T_TOKENS * 4;
  float* w1v     = (float*)w;    w += (size_t)T_TOKENS * 4;
  int*   cnt     = (int*)w;      w += 64;
  float* probs   = (float*)w;    w += 64;
  int*   seg     = (int*)w;      w += 128;

  // fused gemm1 needs a second P region; fall back to sequential if tight
  size_t used = (size_t)(w - (char*)d_ws);
  bool fused = (used + PSZ + 1024) <= ws_size;
  ushort_t* Ps = fused ? (ushort_t*)w : Pr;

  // fp32 -> bf16 (7 tensors) + gate scoring, one dispatch
  k_cvt_score<<<33792, 256, 0, stream>>>(x, w1, w2, w3, sw1, sw2, sw3, gw,
                                         x_bf, w1b, w2b, w3b, sw1b, sw2b, sw3b,
                                         sel0, sel1, w0v, w1v);

  k_compact<<<NEXP, 256, 0, stream>>>(sel0, sel1, w0v, w1v,
                                      toklist, wlist, cnt, probs);
  k_offsets<<<1, 64, 0, stream>>>(cnt, probs, seg, loss);

  if (fused) {
    k_gemm1<<<dim3(64, 32, 17), 256, 0, stream>>>(
        x_bf, w1b, w3b, sw1b, sw3b, sb1, sb3, Pr, Ps,
        toklist, cnt, seg, 0);
    // shared gemm2 first (plain store + bias), then routed (atomicAdd on top)
    k_gemm2<<<dim3(64, 8, 1), 256, 0, stream>>>(
        Pr, Ps, w2b, sw2b, sb2, out, toklist, wlist, cnt, seg, 16);
    k_gemm2<<<dim3(64, 8, 16), 256, 0, stream>>>(
        Pr, Ps, w2b, sw2b, sb2, out, toklist, wlist, cnt, seg, 0);
  } else {
    // sequential fallback (Ps aliases Pr): shared chain then routed chain
    k_gemm1<<<dim3(64, 32, 1), 256, 0, stream>>>(
        x_bf, w1b, w3b, sw1b, sw3b, sb1, sb3, Pr, Ps,
        toklist, cnt, seg, 16);
    k_gemm2<<<dim3(64, 8, 1), 256, 0, stream>>>(
        Pr, Ps, w2b, sw2b, sb2, out, toklist, wlist, cnt, seg, 16);
    k_gemm1<<<dim3(64, 16, 16), 256, 0, stream>>>(
        x_bf, w1b, w3b, sw1b, sw3b, sb1, sb3, Pr, Ps,
        toklist, cnt, seg, 0);
    k_gemm2<<<dim3(64, 8, 16), 256, 0, stream>>>(
        Pr, Ps, w2b, sw2b, sb2, out, toklist, wlist, cnt, seg, 0);
  }
}